// Round 6
// baseline (443.960 us; speedup 1.0000x reference)
//
#include <hip/hip_runtime.h>
#include <hip/hip_bf16.h>

#define D_MODEL 768
#define NH 12
#define DK 64
#define RQ 6
#define RK 2
#define RV 2
#define BATCH 8
#define SEQ 4096
#define NPOS (BATCH*SEQ)

typedef _Float16 v8h __attribute__((ext_vector_type(8)));
typedef float v4f __attribute__((ext_vector_type(4)));

// Async global->LDS DMA, 16B per lane. LDS dest is wave-uniform base;
// HW writes base + lane*16 (m104/m108: no per-lane scatter, no padding).
__device__ __forceinline__ void async16(const _Float16* g, _Float16* l) {
    __builtin_amdgcn_global_load_lds(
        (const __attribute__((address_space(1))) _Float16*)g,
        (__attribute__((address_space(3))) _Float16*)l, 16, 0, 0);
}

// ---------------------------------------------------------------------------
// x (fp32) -> xh (fp16), vectorized 8-wide.
// ---------------------------------------------------------------------------
__global__ __launch_bounds__(256) void cvt_fp16(
    const float4* __restrict__ x, v8h* __restrict__ xh, int nchunks)
{
    int i = blockIdx.x * 256 + threadIdx.x;
    const int stride = gridDim.x * 256;
    for (; i < nchunks; i += stride) {
        float4 a = x[(size_t)i*2], b = x[(size_t)i*2 + 1];
        v8h h;
        h[0]=(_Float16)a.x; h[1]=(_Float16)a.y; h[2]=(_Float16)a.z; h[3]=(_Float16)a.w;
        h[4]=(_Float16)b.x; h[5]=(_Float16)b.y; h[6]=(_Float16)b.z; h[7]=(_Float16)b.w;
        xh[i] = h;
    }
}

// ---------------------------------------------------------------------------
// Repack (fp32 -> fp16): WcatT[n][k] = concat-weights transposed, bcat[n] fp32;
// WoT[n][k] = Wo[k][n]. n in [760,768) zero-padded.
// ---------------------------------------------------------------------------
__global__ __launch_bounds__(256) void repack(
    const float* __restrict__ Waq, const float* __restrict__ baq,
    const float* __restrict__ Wbq, const float* __restrict__ bbq,
    const float* __restrict__ Wak, const float* __restrict__ bak,
    const float* __restrict__ Wbk, const float* __restrict__ bbk,
    const float* __restrict__ Wav, const float* __restrict__ bav,
    const float* __restrict__ Wbv, const float* __restrict__ bbv,
    const float* __restrict__ Wo,
    _Float16* __restrict__ WcatT, _Float16* __restrict__ WoT,
    float* __restrict__ bcat)
{
    const int n = blockIdx.x;   // 0..767
    const int t = threadIdx.x;
    const float* W = nullptr; const float* bsrc = nullptr;
    int cols = 0, col = 0;
    if      (n <  72) { W=Waq; bsrc=baq; cols=72;  col=n;     }
    else if (n < 456) { W=Wbq; bsrc=bbq; cols=384; col=n-72;  }
    else if (n < 480) { W=Wak; bsrc=bak; cols=24;  col=n-456; }
    else if (n < 608) { W=Wbk; bsrc=bbk; cols=128; col=n-480; }
    else if (n < 632) { W=Wav; bsrc=bav; cols=24;  col=n-608; }
    else if (n < 760) { W=Wbv; bsrc=bbv; cols=128; col=n-632; }
    for (int k = t; k < 768; k += 256) {
        WcatT[(size_t)n*768 + k] = W ? (_Float16)W[(size_t)k*cols + col] : (_Float16)0.f;
        WoT[(size_t)n*768 + k]   = (_Float16)Wo[(size_t)k*768 + n];
    }
    if (t == 0) bcat[n] = W ? bsrc[col] : 0.f;
}

// ---------------------------------------------------------------------------
// MFMA GEMM (m97-style): C(Mx768) = A @ BT^T + bias. A,BT fp16 row-major-k.
// 128x128 tile, BK=64, 4 waves x (4x4) mfma_f32_16x16x32_f16, 32 MFMA/barrier.
// All staging via async global_load_lds (16B/lane), LDS [kc(8)][row(128)]
// 16B chunks, 32 KB total. XCD swizzle as round 5 (FETCH 308->62 MB).
// MODE 0: epilogue bias+rope, fp16 P out. MODE 1: epilogue bias, fp32 Y out.
// ---------------------------------------------------------------------------
template<int MODE>
__global__ __launch_bounds__(256) void mfma_gemm(
    const _Float16* __restrict__ A,
    const _Float16* __restrict__ BT,
    const float* __restrict__ bias,
    const float* __restrict__ rope,
    void* __restrict__ Cout)
{
    const int t = threadIdx.x;
    const int lane = t & 63;
    const int wave = t >> 6;

    // XCD-aware swizzle of the 1536-block grid (6 col x 256 row tiles)
    const int flat = blockIdx.y * 6 + blockIdx.x;
    const int xcd = flat & 7;
    const int sub = flat >> 3;          // 0..191
    const int ct  = sub % 6;
    const int rt  = xcd * 32 + sub / 6; // 0..255
    const int row0 = rt * 128;
    const int col0 = ct * 128;

    const int wrow = (wave >> 1) * 64;
    const int wcol = (wave & 1) * 64;
    const int q = lane >> 4;   // k-subchunk for fragments
    const int m = lane & 15;

    __shared__ _Float16 As[8*128*8];   // chunk idx = kc*128 + row (16B chunks)
    __shared__ _Float16 Bs[8*128*8];

    v4f acc[4][4];
    #pragma unroll
    for (int i = 0; i < 4; ++i)
        #pragma unroll
        for (int j = 0; j < 4; ++j)
            acc[i][j] = (v4f){0.f, 0.f, 0.f, 0.f};

    const v8h* gA = (const v8h*)A;   // row stride 96 chunks
    const v8h* gB = (const v8h*)BT;

    for (int k0 = 0; k0 < 768; k0 += 64) {
        const int kb = k0 >> 3;
        __syncthreads();
        #pragma unroll
        for (int j = 0; j < 4; ++j) {
            const int id = wave*4 + j;      // 0..15
            const int kc = id & 7;
            const int hf = id >> 3;         // row half
            async16((const _Float16*)(gA + (size_t)(row0 + hf*64 + lane)*96 + kb + kc),
                    &As[(kc*128 + hf*64)*8]);
            async16((const _Float16*)(gB + (size_t)(col0 + hf*64 + lane)*96 + kb + kc),
                    &Bs[(kc*128 + hf*64)*8]);
        }
        __syncthreads();

        #pragma unroll
        for (int ss = 0; ss < 2; ++ss) {
            v8h af[4], bf[4];
            #pragma unroll
            for (int mi = 0; mi < 4; ++mi)
                af[mi] = *(const v8h*)&As[((ss*4 + q)*128 + wrow + mi*16 + m)*8];
            #pragma unroll
            for (int ni = 0; ni < 4; ++ni)
                bf[ni] = *(const v8h*)&Bs[((ss*4 + q)*128 + wcol + ni*16 + m)*8];
            #pragma unroll
            for (int mi = 0; mi < 4; ++mi)
                #pragma unroll
                for (int ni = 0; ni < 4; ++ni)
                    acc[mi][ni] = __builtin_amdgcn_mfma_f32_16x16x32_f16(
                        af[mi], bf[ni], acc[mi][ni], 0, 0, 0);
        }
    }

    // Epilogue. C/D layout: col = lane&15, row = (lane>>4)*4 + reg.
    #pragma unroll
    for (int mi = 0; mi < 4; ++mi) {
        #pragma unroll
        for (int i = 0; i < 4; ++i) {
            const int grow = row0 + wrow + mi*16 + q*4 + i;
            #pragma unroll
            for (int ni = 0; ni < 4; ++ni) {
                const int gcol = col0 + wcol + ni*16 + m;
                float v = acc[mi][ni][i] + bias[gcol];
                if (MODE == 0) {
                    const int s = grow & 4095;
                    if (gcol >= 72 && gcol < 456)
                        v *= rope[s*64 + ((gcol - 72) & 63)];
                    else if (gcol >= 480 && gcol < 608)
                        v *= rope[s*64 + ((gcol - 480) & 63)];
                    ((_Float16*)Cout)[(size_t)grow*768 + gcol] = (_Float16)v;
                } else {
                    ((float*)Cout)[(size_t)grow*768 + gcol] = v;
                }
            }
        }
    }
}

// ---------------------------------------------------------------------------
// Factorized per-position attention (rope already in P, P fp16).
//   G[r,r'] = (bq_r . bk_r')/8 ; scores = aq^T (G ak) ; attn = softmax
//   c = attn av^T ; out[h,d] = c[h,0] bv[0,d] + c[h,1] bv[1,d]
// 8 positions per 256-thread block. O fp16, layout [b][h][s][d].
// ---------------------------------------------------------------------------
__global__ __launch_bounds__(256) void tpa_attn_f(
    const _Float16* __restrict__ P,
    _Float16* __restrict__ O)
{
    const int t = threadIdx.x;
    const int pos0 = blockIdx.x * 8;

    __shared__ float proj[8][772];   // row pad 768->772
    __shared__ float Gs[8][12];
    __shared__ float sc[8][160];     // 12 rows x stride 13
    __shared__ float cs[8][24];

    // load 8 P-rows (fp16 x8 vector loads)
    const v8h* gp = (const v8h*)P;
    for (int i = t; i < 8*96; i += 256) {
        int p = i / 96, c = i - p*96;
        v8h u = gp[(size_t)(pos0 + p)*96 + c];
        #pragma unroll
        for (int j = 0; j < 8; ++j) proj[p][c*8+j] = (float)u[j];
    }
    __syncthreads();

    // Gram matrix: 8 pos x 12 (r,r') pairs
    if (t < 96) {
        int p = t / 12, u = t - (t/12)*12, r = u >> 1, r2 = u & 1;
        const float* bq = &proj[p][72  + r*64];
        const float* bk = &proj[p][480 + r2*64];
        const int ph = (r*8 + r2*16) & 63;
        float acc = 0.f;
        for (int i = 0; i < 64; ++i) {
            int d = (i + ph) & 63;
            acc = fmaf(bq[d], bk[d], acc);
        }
        Gs[p][u] = acc * 0.125f;
    }
    __syncthreads();

    // scores: 8 pos x 144 (h,g)
    for (int i = t; i < 8*144; i += 256) {
        int p = i / 144, v = i - p*144, h = v / 12, g = v - (v/12)*12;
        float s = 0.f;
        #pragma unroll
        for (int r = 0; r < RQ; ++r) {
            float mg = fmaf(Gs[p][r*2+1], proj[p][468 + g],
                            Gs[p][r*2+0] * proj[p][456 + g]);
            s = fmaf(proj[p][r*12 + h], mg, s);
        }
        sc[p][h*13 + g] = s;
    }
    __syncthreads();

    // softmax over g: 96 rows
    if (t < 96) {
        int p = t / 12, h = t - (t/12)*12;
        float* row = &sc[p][h*13];
        float mx = -1e30f;
        #pragma unroll
        for (int g = 0; g < NH; ++g) mx = fmaxf(mx, row[g]);
        float sum = 0.f;
        #pragma unroll
        for (int g = 0; g < NH; ++g) { float e = __expf(row[g]-mx); row[g] = e; sum += e; }
        float inv = 1.0f / sum;
        #pragma unroll
        for (int g = 0; g < NH; ++g) row[g] *= inv;
    }
    __syncthreads();

    // c[h,r'] = attn . av^T : 8 pos x 24
    if (t < 192) {
        int p = t / 24, u = t - (t/24)*24, h = u >> 1, r2 = u & 1;
        float acc = 0.f;
        #pragma unroll
        for (int g = 0; g < NH; ++g)
            acc = fmaf(sc[p][h*13+g], proj[p][608 + r2*12 + g], acc);
        cs[p][h*2 + r2] = acc;
    }
    __syncthreads();

    // out: 8 pos x 768, d fastest for coalesced fp16 stores
    for (int i = t; i < 8*768; i += 256) {
        int p = i / 768, j = i - p*768, h = j >> 6, d = j & 63;
        int pos = pos0 + p, b = pos >> 12, s = pos & 4095;
        float val = fmaf(cs[p][h*2+1], proj[p][632 + 64 + d],
                         cs[p][h*2+0] * proj[p][632 + d]);
        O[(((size_t)b*NH + h)*SEQ + s)*DK + d] = (_Float16)val;
    }
}

extern "C" void kernel_launch(void* const* d_in, const int* in_sizes, int n_in,
                              void* d_out, int out_size, void* d_ws, size_t ws_size,
                              hipStream_t stream) {
    const float* x    = (const float*)d_in[0];
    const float* rope = (const float*)d_in[1];
    const float* Waq  = (const float*)d_in[2];
    const float* baq  = (const float*)d_in[3];
    const float* Wbq  = (const float*)d_in[4];
    const float* bbq  = (const float*)d_in[5];
    const float* Wak  = (const float*)d_in[6];
    const float* bak  = (const float*)d_in[7];
    const float* Wbk  = (const float*)d_in[8];
    const float* bbk  = (const float*)d_in[9];
    const float* Wav  = (const float*)d_in[10];
    const float* bav  = (const float*)d_in[11];
    const float* Wbv  = (const float*)d_in[12];
    const float* bbv  = (const float*)d_in[13];
    const float* Wo   = (const float*)d_in[14];
    const float* bo   = (const float*)d_in[15];

    // ws (unchanged footprint ~52.7 MB): fp16 weights + fp16 O
    char* ws = (char*)d_ws;
    _Float16* WcatT = (_Float16*)(ws);                 // 1,179,648 B
    _Float16* WoT   = (_Float16*)(ws + 1179648);       // 1,179,648 B
    float*    bcat  = (float*)(ws + 2359296);          // 3,072 B
    _Float16* O     = (_Float16*)(ws + 2363392);       // 50,331,648 B

    // d_out (96 MB) doubles as scratch: xh fp16 (48 MB) | P fp16 (48 MB).
    // Both fully consumed before the final GEMM overwrites d_out with Y.
    _Float16* xh = (_Float16*)d_out;
    _Float16* P  = (_Float16*)((char*)d_out + 50331648);

    cvt_fp16<<<3072, 256, 0, stream>>>((const float4*)x, (v8h*)xh, NPOS*96);

    repack<<<768, 256, 0, stream>>>(Waq, baq, Wbq, bbq, Wak, bak, Wbk, bbk,
                                    Wav, bav, Wbv, bbv, Wo, WcatT, WoT, bcat);

    dim3 gg(6, 256);
    mfma_gemm<0><<<gg, 256, 0, stream>>>(xh, WcatT, bcat, rope, P);

    tpa_attn_f<<<NPOS/8, 256, 0, stream>>>(P, O);

    mfma_gemm<1><<<gg, 256, 0, stream>>>(O, WoT, bo, nullptr, d_out);
}